// Round 1
// baseline (270.756 us; speedup 1.0000x reference)
//
#include <hip/hip_runtime.h>
#include <stdint.h>

// Problem constants: B=4, N=8192, G=512, E=512, D=3E=1536
#define NB 4
#define NP 8192
#define NG 512
#define DF 1536
#define NC 512

using f32x4   = __attribute__((ext_vector_type(4))) float;
using bf16x8  = __attribute__((ext_vector_type(8))) __bf16;
using ushort8v = __attribute__((ext_vector_type(8))) unsigned short;

__device__ __forceinline__ unsigned short f32_to_bf16(float f) {
  unsigned int u = __float_as_uint(f);
  u += 0x7fffu + ((u >> 16) & 1u);   // round-to-nearest-even
  return (unsigned short)(u >> 16);
}

// ---------------- BN constant folding: s = g*rsqrt(v+eps), t = be - m*s -----
__global__ __launch_bounds__(256) void scales_kernel(
    const float* __restrict__ g1, const float* __restrict__ be1,
    const float* __restrict__ m1, const float* __restrict__ v1,
    const float* __restrict__ g2, const float* __restrict__ be2,
    const float* __restrict__ m2, const float* __restrict__ v2,
    float* __restrict__ s1, float* __restrict__ t1,
    float* __restrict__ s2, float* __restrict__ t2)
{
  int i = blockIdx.x * 256 + threadIdx.x;
  if (i < 512) {
    float sa = g1[i] / sqrtf(v1[i] + 1e-5f);
    s1[i] = sa; t1[i] = be1[i] - m1[i] * sa;
    float sb = g2[i] / sqrtf(v2[i] + 1e-5f);
    s2[i] = sb; t2[i] = be2[i] - m2[i] * sb;
  }
}

// ---------------- cast fused=concat(H4,H8,H12) [2048,1536] f32->bf16 --------
__global__ __launch_bounds__(256) void cast_fused_kernel(
    const float* __restrict__ H4, const float* __restrict__ H8,
    const float* __restrict__ H12, unsigned short* __restrict__ outp)
{
  const int t = blockIdx.x * 256 + threadIdx.x;   // < 2048*384
  const int row = t / 384;
  const int c4 = (t - row * 384) * 4;             // 0..1532
  const float* src = (c4 < 512) ? H4 : (c4 < 1024 ? H8 : H12);
  float4 v = *(const float4*)&src[(size_t)row * 512 + (c4 & 511)];
  ushort4 o;
  o.x = f32_to_bf16(v.x); o.y = f32_to_bf16(v.y);
  o.z = f32_to_bf16(v.z); o.w = f32_to_bf16(v.w);
  *(ushort4*)&outp[(size_t)row * 1536 + c4] = o;
}

// ---------------- generic f32 -> bf16 cast (n4 float4 groups) ---------------
__global__ __launch_bounds__(256) void cast_bf16_kernel(
    const float* __restrict__ in, unsigned short* __restrict__ outp, int n4)
{
  const int t = blockIdx.x * 256 + threadIdx.x;
  if (t < n4) {
    float4 v = *(const float4*)&in[(size_t)t * 4];
    ushort4 o;
    o.x = f32_to_bf16(v.x); o.y = f32_to_bf16(v.y);
    o.z = f32_to_bf16(v.z); o.w = f32_to_bf16(v.w);
    *(ushort4*)&outp[(size_t)t * 4] = o;
  }
}

// ---------------- KNN: per point top-3 smallest dists + inv-dist weights ----
__global__ __launch_bounds__(256) void knn_kernel(
    const float* __restrict__ xyz, const float* __restrict__ centers,
    int* __restrict__ oidx, float* __restrict__ ow)
{
  __shared__ float cx[NG], cy[NG], cz[NG], cc[NG];
  const int b = blockIdx.y;
  for (int i = threadIdx.x; i < NG; i += 256) {
    float c0 = centers[((size_t)b * NG + i) * 3 + 0];
    float c1 = centers[((size_t)b * NG + i) * 3 + 1];
    float c2 = centers[((size_t)b * NG + i) * 3 + 2];
    cx[i] = c0; cy[i] = c1; cz[i] = c2;
    cc[i] = c0 * c0 + c1 * c1 + c2 * c2;
  }
  __syncthreads();
  const int p = blockIdx.x * 256 + threadIdx.x;
  const size_t pi = (size_t)b * NP + p;
  float x0 = xyz[pi * 3 + 0], x1 = xyz[pi * 3 + 1], x2 = xyz[pi * 3 + 2];
  float xx = x0 * x0 + x1 * x1 + x2 * x2;
  float d0 = 3.4e38f, d1 = 3.4e38f, d2 = 3.4e38f;
  int i0 = 0, i1 = 0, i2 = 0;
  for (int g = 0; g < NG; ++g) {
    float dot = x0 * cx[g] + x1 * cy[g] + x2 * cz[g];
    float d = xx + cc[g] - 2.0f * dot;     // same expanded form as reference
    if (d < d2) {                          // strict <: lower index wins ties
      if (d < d1) {
        d2 = d1; i2 = i1;
        if (d < d0) { d1 = d0; i1 = i0; d0 = d; i0 = g; }
        else        { d1 = d;  i1 = g; }
      } else { d2 = d; i2 = g; }
    }
  }
  float r0 = 1.0f / (d0 + 1e-8f), r1 = 1.0f / (d1 + 1e-8f), r2 = 1.0f / (d2 + 1e-8f);
  float inv = 1.0f / (r0 + r1 + r2);
  ow[pi * 3 + 0] = r0 * inv; ow[pi * 3 + 1] = r1 * inv; ow[pi * 3 + 2] = r2 * inv;
  oidx[pi * 3 + 0] = i0; oidx[pi * 3 + 1] = i1; oidx[pi * 3 + 2] = i2;
}

// ---------------- bf16 MFMA GEMM, B^T layout: out[m,n]=f(s[n]*(A.Bw+b[n])+t[n])
// A [M,K] bf16 row-major, Bw [N,K] bf16 row-major. 128x128 tile, BK=32,
// 256 threads = 4 waves in 2x2, each wave 64x64 via 4x4 mfma_f32_16x16x32_bf16.
template <bool RELU>
__global__ __launch_bounds__(256) void gemm_bt_kernel(
    const unsigned short* __restrict__ A, const unsigned short* __restrict__ Bw,
    float* __restrict__ outp,
    const float* __restrict__ svec, const float* __restrict__ bvec,
    const float* __restrict__ tvec, int M, int N, int K)
{
  __shared__ unsigned short As[128 * 32];
  __shared__ unsigned short Bs[128 * 32];
  const int tid  = threadIdx.x;
  const int lane = tid & 63;
  const int wv   = tid >> 6;
  const int wm   = wv >> 1, wn = wv & 1;
  const int m0   = blockIdx.x * 128;
  const int n0   = blockIdx.y * 128;

  const int crow = tid >> 2;            // 0..63
  const int ccol = (tid & 3) * 8;       // 0,8,16,24

  const unsigned short* Arow = A  + (size_t)(m0 + crow) * K + ccol;
  const unsigned short* Brow = Bw + (size_t)(n0 + crow) * K + ccol;

  const f32x4 vzero = {0.f, 0.f, 0.f, 0.f};
  f32x4 acc[4][4];
#pragma unroll
  for (int i = 0; i < 4; ++i)
#pragma unroll
    for (int j = 0; j < 4; ++j) acc[i][j] = vzero;

  for (int k0 = 0; k0 < K; k0 += 32) {
    uint4 a0 = *(const uint4*)(Arow + k0);
    uint4 a1 = *(const uint4*)(Arow + (size_t)64 * K + k0);
    uint4 b0 = *(const uint4*)(Brow + k0);
    uint4 b1 = *(const uint4*)(Brow + (size_t)64 * K + k0);
    if (k0) __syncthreads();            // previous tile's reads must finish
    *(uint4*)&As[crow * 32 + ccol]        = a0;
    *(uint4*)&As[(crow + 64) * 32 + ccol] = a1;
    *(uint4*)&Bs[crow * 32 + ccol]        = b0;
    *(uint4*)&Bs[(crow + 64) * 32 + ccol] = b1;
    __syncthreads();

    bf16x8 af[4], bfr[4];
#pragma unroll
    for (int mi = 0; mi < 4; ++mi) {
      ushort8v r = *(const ushort8v*)&As[(wm * 64 + mi * 16 + (lane & 15)) * 32 + (lane >> 4) * 8];
      af[mi] = __builtin_bit_cast(bf16x8, r);
    }
#pragma unroll
    for (int ni = 0; ni < 4; ++ni) {
      ushort8v r = *(const ushort8v*)&Bs[(wn * 64 + ni * 16 + (lane & 15)) * 32 + (lane >> 4) * 8];
      bfr[ni] = __builtin_bit_cast(bf16x8, r);
    }
#pragma unroll
    for (int mi = 0; mi < 4; ++mi)
#pragma unroll
      for (int ni = 0; ni < 4; ++ni)
        acc[mi][ni] = __builtin_amdgcn_mfma_f32_16x16x32_bf16(af[mi], bfr[ni], acc[mi][ni], 0, 0, 0);
  }

  // C/D layout: n = lane&15, m = (lane>>4)*4 + reg   [m89-verified]
#pragma unroll
  for (int mi = 0; mi < 4; ++mi) {
    int mbase = m0 + wm * 64 + mi * 16 + (lane >> 4) * 4;
#pragma unroll
    for (int ni = 0; ni < 4; ++ni) {
      int n = n0 + wn * 64 + ni * 16 + (lane & 15);
      float s = svec[n], bb = bvec[n], t = tvec[n];
      f32x4 v = acc[mi][ni];
#pragma unroll
      for (int r = 0; r < 4; ++r) {
        float val = s * (v[r] + bb) + t;
        if (RELU) val = fmaxf(val, 0.f);
        outp[(size_t)(mbase + r) * N + n] = val;
      }
    }
  }
}

// ---------------- gather + interp + ReLU -> h1 bf16 [32768,512] -------------
__global__ __launch_bounds__(256) void interp_kernel(
    const float* __restrict__ Amat, const int* __restrict__ nidx,
    const float* __restrict__ nw, unsigned short* __restrict__ h1)
{
  const int pbase = blockIdx.x * 4;
#pragma unroll
  for (int q = 0; q < 4; ++q) {
    const int pp = pbase + q;
    const int b = pp >> 13;                        // / 8192
    const int i0 = nidx[pp * 3 + 0], i1 = nidx[pp * 3 + 1], i2 = nidx[pp * 3 + 2];
    const float w0 = nw[pp * 3 + 0], w1v = nw[pp * 3 + 1], w2v = nw[pp * 3 + 2];
    const float* A0 = Amat + ((size_t)(b * 512 + i0)) * 512;
    const float* A1 = Amat + ((size_t)(b * 512 + i1)) * 512;
    const float* A2 = Amat + ((size_t)(b * 512 + i2)) * 512;
    unsigned short* hp = h1 + (size_t)pp * 512;
    for (int c = threadIdx.x; c < 512; c += 256) {
      float v = w0 * A0[c] + w1v * A1[c] + w2v * A2[c];
      hp[c] = f32_to_bf16(fmaxf(v, 0.0f));
    }
  }
}

extern "C" void kernel_launch(void* const* d_in, const int* in_sizes, int n_in,
                              void* d_out, int out_size, void* d_ws, size_t ws_size,
                              hipStream_t stream) {
  const float* xyz     = (const float*)d_in[0];
  const float* centers = (const float*)d_in[1];
  const float* H4      = (const float*)d_in[2];
  const float* H8      = (const float*)d_in[3];
  const float* H12     = (const float*)d_in[4];
  const float* w1      = (const float*)d_in[5];
  const float* b1      = (const float*)d_in[6];
  const float* g1      = (const float*)d_in[7];
  const float* be1     = (const float*)d_in[8];
  const float* m1      = (const float*)d_in[9];
  const float* v1      = (const float*)d_in[10];
  const float* w2      = (const float*)d_in[11];
  const float* b2      = (const float*)d_in[12];
  const float* g2      = (const float*)d_in[13];
  const float* be2     = (const float*)d_in[14];
  const float* m2      = (const float*)d_in[15];
  const float* v2      = (const float*)d_in[16];
  float* outp = (float*)d_out;

  char* ws = (char*)d_ws;
  unsigned short* fusedb = (unsigned short*)(ws);                // 6,291,456 B
  unsigned short* w1b    = (unsigned short*)(ws + 6291456);      // 1,572,864 B
  unsigned short* w2b    = (unsigned short*)(ws + 7864320);      //   524,288 B
  float*          Amat   = (float*)         (ws + 8388608);      // 4,194,304 B
  unsigned short* h1     = (unsigned short*)(ws + 12582912);     // 33,554,432 B
  int*            nidx   = (int*)           (ws + 46137344);     //   393,216 B
  float*          nw     = (float*)         (ws + 46530560);     //   393,216 B
  float*          s1     = (float*)         (ws + 46923776);
  float* t1 = s1 + 512; float* s2 = t1 + 512; float* t2 = s2 + 512;

  scales_kernel<<<2, 256, 0, stream>>>(g1, be1, m1, v1, g2, be2, m2, v2, s1, t1, s2, t2);
  cast_fused_kernel<<<3072, 256, 0, stream>>>(H4, H8, H12, fusedb);
  cast_bf16_kernel<<<768, 256, 0, stream>>>(w1, w1b, 196608);   // 512*1536/4
  cast_bf16_kernel<<<256, 256, 0, stream>>>(w2, w2b, 65536);    // 512*512/4
  knn_kernel<<<dim3(32, 4), 256, 0, stream>>>(xyz, centers, nidx, nw);
  // fusedW + BN1 fold: Amat[m,n] = s1[n]*(fused.w1^T + b1[n]) + t1[n]
  gemm_bt_kernel<false><<<dim3(16, 4), 256, 0, stream>>>(
      fusedb, w1b, Amat, s1, b1, t1, 2048, 512, 1536);
  interp_kernel<<<8192, 256, 0, stream>>>(Amat, nidx, nw, h1);
  // out = relu(s2*(h1.w2^T + b2) + t2)
  gemm_bt_kernel<true><<<dim3(256, 4), 256, 0, stream>>>(
      h1, w2b, outp, s2, b2, t2, 32768, 512, 512);
}

// Round 2
// 214.597 us; speedup vs baseline: 1.2617x; 1.2617x over previous
//
#include <hip/hip_runtime.h>
#include <stdint.h>

// Problem constants: B=4, N=8192, G=512, E=512, D=3E=1536
#define NB 4
#define NP 8192
#define NG 512
#define DF 1536
#define NC 512

using f32x4   = __attribute__((ext_vector_type(4))) float;
using bf16x8  = __attribute__((ext_vector_type(8))) __bf16;
using ushort8v = __attribute__((ext_vector_type(8))) unsigned short;

__device__ __forceinline__ unsigned short f32_to_bf16(float f) {
  unsigned int u = __float_as_uint(f);
  u += 0x7fffu + ((u >> 16) & 1u);   // round-to-nearest-even
  return (unsigned short)(u >> 16);
}

// async global->LDS 16B per lane; lds base must be wave-uniform, HW adds lane*16
__device__ __forceinline__ void glds16(const unsigned short* g, unsigned short* l) {
  __builtin_amdgcn_global_load_lds(
      (const __attribute__((address_space(1))) void*)g,
      (__attribute__((address_space(3))) void*)l, 16, 0, 0);
}

// ---------------- BN constant folding: s = g*rsqrt(v+eps), t = be - m*s -----
__global__ __launch_bounds__(256) void scales_kernel(
    const float* __restrict__ g1, const float* __restrict__ be1,
    const float* __restrict__ m1, const float* __restrict__ v1,
    const float* __restrict__ g2, const float* __restrict__ be2,
    const float* __restrict__ m2, const float* __restrict__ v2,
    float* __restrict__ s1, float* __restrict__ t1,
    float* __restrict__ s2, float* __restrict__ t2)
{
  int i = blockIdx.x * 256 + threadIdx.x;
  if (i < 512) {
    float sa = g1[i] / sqrtf(v1[i] + 1e-5f);
    s1[i] = sa; t1[i] = be1[i] - m1[i] * sa;
    float sb = g2[i] / sqrtf(v2[i] + 1e-5f);
    s2[i] = sb; t2[i] = be2[i] - m2[i] * sb;
  }
}

// ---------------- cast fused=concat(H4,H8,H12) [2048,1536] f32->bf16 --------
__global__ __launch_bounds__(256) void cast_fused_kernel(
    const float* __restrict__ H4, const float* __restrict__ H8,
    const float* __restrict__ H12, unsigned short* __restrict__ outp)
{
  const int t = blockIdx.x * 256 + threadIdx.x;   // < 2048*384
  const int row = t / 384;
  const int c4 = (t - row * 384) * 4;             // 0..1532
  const float* src = (c4 < 512) ? H4 : (c4 < 1024 ? H8 : H12);
  float4 v = *(const float4*)&src[(size_t)row * 512 + (c4 & 511)];
  ushort4 o;
  o.x = f32_to_bf16(v.x); o.y = f32_to_bf16(v.y);
  o.z = f32_to_bf16(v.z); o.w = f32_to_bf16(v.w);
  *(ushort4*)&outp[(size_t)row * 1536 + c4] = o;
}

// ---------------- generic f32 -> bf16 cast (n4 float4 groups) ---------------
__global__ __launch_bounds__(256) void cast_bf16_kernel(
    const float* __restrict__ in, unsigned short* __restrict__ outp, int n4)
{
  const int t = blockIdx.x * 256 + threadIdx.x;
  if (t < n4) {
    float4 v = *(const float4*)&in[(size_t)t * 4];
    ushort4 o;
    o.x = f32_to_bf16(v.x); o.y = f32_to_bf16(v.y);
    o.z = f32_to_bf16(v.z); o.w = f32_to_bf16(v.w);
    *(ushort4*)&outp[(size_t)t * 4] = o;
  }
}

// ---------------- KNN v2: 4 lanes per point, branchless top-3, shfl merge ---
// grid (128, 4) x 256 thr: 64 points/block, lanes q=0..3 scan centers q*128..+128
__global__ __launch_bounds__(256) void knn_kernel(
    const float* __restrict__ xyz, const float* __restrict__ centers,
    int* __restrict__ oidx, float* __restrict__ ow)
{
  __shared__ float4 cs[NG];
  const int b = blockIdx.y;
  for (int i = threadIdx.x; i < NG; i += 256) {
    float c0 = centers[((size_t)b * NG + i) * 3 + 0];
    float c1 = centers[((size_t)b * NG + i) * 3 + 1];
    float c2 = centers[((size_t)b * NG + i) * 3 + 2];
    float4 v; v.x = c0; v.y = c1; v.z = c2; v.w = c0 * c0 + c1 * c1 + c2 * c2;
    cs[i] = v;
  }
  __syncthreads();
  const int t = blockIdx.x * 256 + threadIdx.x;   // 0..32767 per batch
  const int p = t >> 2;                            // point index
  const int q = t & 3;                             // center chunk
  const size_t pi = (size_t)b * NP + p;
  const float x0 = xyz[pi * 3 + 0], x1 = xyz[pi * 3 + 1], x2 = xyz[pi * 3 + 2];
  const float xx = x0 * x0 + x1 * x1 + x2 * x2;

  float d0 = 3.4e38f, d1 = 3.4e38f, d2 = 3.4e38f;
  int i0 = 0, i1 = 0, i2 = 0;
  const int gbase = q * 128;
#pragma unroll 4
  for (int j = 0; j < 128; ++j) {
    float4 c = cs[gbase + j];
    float d = xx + c.w - 2.0f * (x0 * c.x + x1 * c.y + x2 * c.z);
    int g = gbase + j;
    bool c0 = d < d0, c1 = d < d1, c2 = d < d2;
    float nd2 = c1 ? d1 : (c2 ? d : d2); int ni2 = c1 ? i1 : (c2 ? g : i2);
    float nd1 = c0 ? d0 : (c1 ? d : d1); int ni1 = c0 ? i0 : (c1 ? g : i1);
    d0 = c0 ? d : d0;                    i0 = c0 ? g : i0;
    d1 = nd1; i1 = ni1; d2 = nd2; i2 = ni2;
  }
  // merge 4 lanes' top-3 (lex tie-break: smaller d, then smaller index)
#pragma unroll
  for (int off = 1; off <= 2; off <<= 1) {
    float e0 = __shfl_xor(d0, off), e1 = __shfl_xor(d1, off), e2 = __shfl_xor(d2, off);
    int j0 = __shfl_xor(i0, off), j1 = __shfl_xor(i1, off), j2 = __shfl_xor(i2, off);
#pragma unroll
    for (int s = 0; s < 3; ++s) {
      float e = (s == 0) ? e0 : (s == 1 ? e1 : e2);
      int   j = (s == 0) ? j0 : (s == 1 ? j1 : j2);
      bool c0 = (e < d0) || (e == d0 && j < i0);
      bool c1 = (e < d1) || (e == d1 && j < i1);
      bool c2 = (e < d2) || (e == d2 && j < i2);
      float nd2 = c1 ? d1 : (c2 ? e : d2); int ni2 = c1 ? i1 : (c2 ? j : i2);
      float nd1 = c0 ? d0 : (c1 ? e : d1); int ni1 = c0 ? i0 : (c1 ? j : i1);
      d0 = c0 ? e : d0;                    i0 = c0 ? j : i0;
      d1 = nd1; i1 = ni1; d2 = nd2; i2 = ni2;
    }
  }
  if (q == 0) {
    float r0 = 1.0f / (d0 + 1e-8f), r1 = 1.0f / (d1 + 1e-8f), r2 = 1.0f / (d2 + 1e-8f);
    float inv = 1.0f / (r0 + r1 + r2);
    ow[pi * 3 + 0] = r0 * inv; ow[pi * 3 + 1] = r1 * inv; ow[pi * 3 + 2] = r2 * inv;
    oidx[pi * 3 + 0] = i0; oidx[pi * 3 + 1] = i1; oidx[pi * 3 + 2] = i2;
  }
}

// ---------------- bf16 MFMA GEMM, B^T layout: out[m,n]=f(s[n]*(A.Bw+b[n])+t[n])
// A [M,K] bf16 row-major, Bw [N,K] bf16 row-major. 128x128 tile, BK=32,
// 256 threads = 4 waves in 2x2, each wave 64x64 via 4x4 mfma_f32_16x16x32_bf16.
// Staging via async global_load_lds (16B/lane); LDS layout has byte offset
// tid*16 per half-tile, i.e. wave-uniform base + lane*16 as HW requires.
template <bool RELU>
__global__ __launch_bounds__(256) void gemm_bt_kernel(
    const unsigned short* __restrict__ A, const unsigned short* __restrict__ Bw,
    float* __restrict__ outp,
    const float* __restrict__ svec, const float* __restrict__ bvec,
    const float* __restrict__ tvec, int M, int N, int K)
{
  __shared__ unsigned short As[128 * 32];
  __shared__ unsigned short Bs[128 * 32];
  const int tid  = threadIdx.x;
  const int lane = tid & 63;
  const int wv   = tid >> 6;
  const int wm   = wv >> 1, wn = wv & 1;
  const int m0   = blockIdx.x * 128;
  const int n0   = blockIdx.y * 128;

  const int crow = tid >> 2;            // 0..63
  const int ccol = (tid & 3) * 8;       // 0,8,16,24

  const unsigned short* Arow = A  + (size_t)(m0 + crow) * K + ccol;
  const unsigned short* Brow = Bw + (size_t)(n0 + crow) * K + ccol;

  // wave-uniform LDS bases (halfword units): rows 0-63 at wv*512, rows 64-127 at +2048
  unsigned short* AsW0 = As + wv * 512;
  unsigned short* AsW1 = As + 2048 + wv * 512;
  unsigned short* BsW0 = Bs + wv * 512;
  unsigned short* BsW1 = Bs + 2048 + wv * 512;

  const f32x4 vzero = {0.f, 0.f, 0.f, 0.f};
  f32x4 acc[4][4];
#pragma unroll
  for (int i = 0; i < 4; ++i)
#pragma unroll
    for (int j = 0; j < 4; ++j) acc[i][j] = vzero;

  for (int k0 = 0; k0 < K; k0 += 32) {
    __syncthreads();                    // prev tile's LDS reads done
    glds16(Arow + k0, AsW0);
    glds16(Arow + (size_t)64 * K + k0, AsW1);
    glds16(Brow + k0, BsW0);
    glds16(Brow + (size_t)64 * K + k0, BsW1);
    __syncthreads();                    // drains vmcnt -> LDS writes visible

    bf16x8 af[4], bfr[4];
#pragma unroll
    for (int mi = 0; mi < 4; ++mi) {
      ushort8v r = *(const ushort8v*)&As[(wm * 64 + mi * 16 + (lane & 15)) * 32 + (lane >> 4) * 8];
      af[mi] = __builtin_bit_cast(bf16x8, r);
    }
#pragma unroll
    for (int ni = 0; ni < 4; ++ni) {
      ushort8v r = *(const ushort8v*)&Bs[(wn * 64 + ni * 16 + (lane & 15)) * 32 + (lane >> 4) * 8];
      bfr[ni] = __builtin_bit_cast(bf16x8, r);
    }
#pragma unroll
    for (int mi = 0; mi < 4; ++mi)
#pragma unroll
      for (int ni = 0; ni < 4; ++ni)
        acc[mi][ni] = __builtin_amdgcn_mfma_f32_16x16x32_bf16(af[mi], bfr[ni], acc[mi][ni], 0, 0, 0);
  }

  // C/D layout: n = lane&15, m = (lane>>4)*4 + reg   [m89-verified]
#pragma unroll
  for (int mi = 0; mi < 4; ++mi) {
    int mbase = m0 + wm * 64 + mi * 16 + (lane >> 4) * 4;
#pragma unroll
    for (int ni = 0; ni < 4; ++ni) {
      int n = n0 + wn * 64 + ni * 16 + (lane & 15);
      float s = svec[n], bb = bvec[n], t = tvec[n];
      f32x4 v = acc[mi][ni];
#pragma unroll
      for (int r = 0; r < 4; ++r) {
        float val = s * (v[r] + bb) + t;
        if (RELU) val = fmaxf(val, 0.f);
        outp[(size_t)(mbase + r) * N + n] = val;
      }
    }
  }
}

// ---------------- gather + interp + ReLU -> h1 bf16 [32768,512] -------------
__global__ __launch_bounds__(256) void interp_kernel(
    const float* __restrict__ Amat, const int* __restrict__ nidx,
    const float* __restrict__ nw, unsigned short* __restrict__ h1)
{
  const int pbase = blockIdx.x * 4;
#pragma unroll
  for (int q = 0; q < 4; ++q) {
    const int pp = pbase + q;
    const int b = pp >> 13;                        // / 8192
    const int i0 = nidx[pp * 3 + 0], i1 = nidx[pp * 3 + 1], i2 = nidx[pp * 3 + 2];
    const float w0 = nw[pp * 3 + 0], w1v = nw[pp * 3 + 1], w2v = nw[pp * 3 + 2];
    const float* A0 = Amat + ((size_t)(b * 512 + i0)) * 512;
    const float* A1 = Amat + ((size_t)(b * 512 + i1)) * 512;
    const float* A2 = Amat + ((size_t)(b * 512 + i2)) * 512;
    unsigned short* hp = h1 + (size_t)pp * 512;
    for (int c = threadIdx.x; c < 512; c += 256) {
      float v = w0 * A0[c] + w1v * A1[c] + w2v * A2[c];
      hp[c] = f32_to_bf16(fmaxf(v, 0.0f));
    }
  }
}

extern "C" void kernel_launch(void* const* d_in, const int* in_sizes, int n_in,
                              void* d_out, int out_size, void* d_ws, size_t ws_size,
                              hipStream_t stream) {
  const float* xyz     = (const float*)d_in[0];
  const float* centers = (const float*)d_in[1];
  const float* H4      = (const float*)d_in[2];
  const float* H8      = (const float*)d_in[3];
  const float* H12     = (const float*)d_in[4];
  const float* w1      = (const float*)d_in[5];
  const float* b1      = (const float*)d_in[6];
  const float* g1      = (const float*)d_in[7];
  const float* be1     = (const float*)d_in[8];
  const float* m1      = (const float*)d_in[9];
  const float* v1      = (const float*)d_in[10];
  const float* w2      = (const float*)d_in[11];
  const float* b2      = (const float*)d_in[12];
  const float* g2      = (const float*)d_in[13];
  const float* be2     = (const float*)d_in[14];
  const float* m2      = (const float*)d_in[15];
  const float* v2      = (const float*)d_in[16];
  float* outp = (float*)d_out;

  char* ws = (char*)d_ws;
  unsigned short* fusedb = (unsigned short*)(ws);                // 6,291,456 B
  unsigned short* w1b    = (unsigned short*)(ws + 6291456);      // 1,572,864 B
  unsigned short* w2b    = (unsigned short*)(ws + 7864320);      //   524,288 B
  float*          Amat   = (float*)         (ws + 8388608);      // 4,194,304 B
  unsigned short* h1     = (unsigned short*)(ws + 12582912);     // 33,554,432 B
  int*            nidx   = (int*)           (ws + 46137344);     //   393,216 B
  float*          nw     = (float*)         (ws + 46530560);     //   393,216 B
  float*          s1     = (float*)         (ws + 46923776);
  float* t1 = s1 + 512; float* s2 = t1 + 512; float* t2 = s2 + 512;

  scales_kernel<<<2, 256, 0, stream>>>(g1, be1, m1, v1, g2, be2, m2, v2, s1, t1, s2, t2);
  cast_fused_kernel<<<3072, 256, 0, stream>>>(H4, H8, H12, fusedb);
  cast_bf16_kernel<<<768, 256, 0, stream>>>(w1, w1b, 196608);   // 512*1536/4
  cast_bf16_kernel<<<256, 256, 0, stream>>>(w2, w2b, 65536);    // 512*512/4
  knn_kernel<<<dim3(128, 4), 256, 0, stream>>>(xyz, centers, nidx, nw);
  // fusedW + BN1 fold: Amat[m,n] = s1[n]*(fused.w1^T + b1[n]) + t1[n]
  gemm_bt_kernel<false><<<dim3(16, 4), 256, 0, stream>>>(
      fusedb, w1b, Amat, s1, b1, t1, 2048, 512, 1536);
  interp_kernel<<<8192, 256, 0, stream>>>(Amat, nidx, nw, h1);
  // out = relu(s2*(h1.w2^T + b2) + t2)
  gemm_bt_kernel<true><<<dim3(256, 4), 256, 0, stream>>>(
      h1, w2b, outp, s2, b2, t2, 32768, 512, 512);
}

// Round 3
// 208.612 us; speedup vs baseline: 1.2979x; 1.0287x over previous
//
#include <hip/hip_runtime.h>
#include <stdint.h>

// Problem constants: B=4, N=8192, G=512, E=512, D=3E=1536
#define NB 4
#define NP 8192
#define NG 512
#define DF 1536
#define NC 512

using f32x4   = __attribute__((ext_vector_type(4))) float;
using bf16x8  = __attribute__((ext_vector_type(8))) __bf16;
using ushort8v = __attribute__((ext_vector_type(8))) unsigned short;

__device__ __forceinline__ unsigned short f32_to_bf16(float f) {
  unsigned int u = __float_as_uint(f);
  u += 0x7fffu + ((u >> 16) & 1u);   // round-to-nearest-even
  return (unsigned short)(u >> 16);
}

// async global->LDS 16B per lane; lds base must be wave-uniform, HW adds lane*16
__device__ __forceinline__ void glds16(const unsigned short* g, unsigned short* l) {
  __builtin_amdgcn_global_load_lds(
      (const __attribute__((address_space(1))) void*)g,
      (__attribute__((address_space(3))) void*)l, 16, 0, 0);
}

// ---------------- BN constant folding: s = g*rsqrt(v+eps), t = be - m*s -----
__global__ __launch_bounds__(256) void scales_kernel(
    const float* __restrict__ g1, const float* __restrict__ be1,
    const float* __restrict__ m1, const float* __restrict__ v1,
    const float* __restrict__ g2, const float* __restrict__ be2,
    const float* __restrict__ m2, const float* __restrict__ v2,
    float* __restrict__ s1, float* __restrict__ t1,
    float* __restrict__ s2, float* __restrict__ t2)
{
  int i = blockIdx.x * 256 + threadIdx.x;
  if (i < 512) {
    float sa = g1[i] / sqrtf(v1[i] + 1e-5f);
    s1[i] = sa; t1[i] = be1[i] - m1[i] * sa;
    float sb = g2[i] / sqrtf(v2[i] + 1e-5f);
    s2[i] = sb; t2[i] = be2[i] - m2[i] * sb;
  }
}

// ---------------- cast fused=concat(H4,H8,H12) [2048,1536] f32->bf16 --------
__global__ __launch_bounds__(256) void cast_fused_kernel(
    const float* __restrict__ H4, const float* __restrict__ H8,
    const float* __restrict__ H12, unsigned short* __restrict__ outp)
{
  const int t = blockIdx.x * 256 + threadIdx.x;   // < 2048*384
  const int row = t / 384;
  const int c4 = (t - row * 384) * 4;             // 0..1532
  const float* src = (c4 < 512) ? H4 : (c4 < 1024 ? H8 : H12);
  float4 v = *(const float4*)&src[(size_t)row * 512 + (c4 & 511)];
  ushort4 o;
  o.x = f32_to_bf16(v.x); o.y = f32_to_bf16(v.y);
  o.z = f32_to_bf16(v.z); o.w = f32_to_bf16(v.w);
  *(ushort4*)&outp[(size_t)row * 1536 + c4] = o;
}

// ---------------- generic f32 -> bf16 cast (n4 float4 groups) ---------------
__global__ __launch_bounds__(256) void cast_bf16_kernel(
    const float* __restrict__ in, unsigned short* __restrict__ outp, int n4)
{
  const int t = blockIdx.x * 256 + threadIdx.x;
  if (t < n4) {
    float4 v = *(const float4*)&in[(size_t)t * 4];
    ushort4 o;
    o.x = f32_to_bf16(v.x); o.y = f32_to_bf16(v.y);
    o.z = f32_to_bf16(v.z); o.w = f32_to_bf16(v.w);
    *(ushort4*)&outp[(size_t)t * 4] = o;
  }
}

// ---------------- KNN: 4 lanes per point, branchless top-3, shfl merge ------
// grid (128, 4) x 256 thr. cs chunk stride 129 (not 128): banks (4q+4j)%32
// distinct per q -> conflict-free 4-address broadcast.
__global__ __launch_bounds__(256) void knn_kernel(
    const float* __restrict__ xyz, const float* __restrict__ centers,
    int* __restrict__ oidx, float* __restrict__ ow)
{
  __shared__ float4 cs[4 * 129];
  const int b = blockIdx.y;
  for (int i = threadIdx.x; i < NG; i += 256) {
    float c0 = centers[((size_t)b * NG + i) * 3 + 0];
    float c1 = centers[((size_t)b * NG + i) * 3 + 1];
    float c2 = centers[((size_t)b * NG + i) * 3 + 2];
    float4 v; v.x = c0; v.y = c1; v.z = c2; v.w = c0 * c0 + c1 * c1 + c2 * c2;
    cs[(i >> 7) * 129 + (i & 127)] = v;
  }
  __syncthreads();
  const int t = blockIdx.x * 256 + threadIdx.x;   // 0..32767 per batch
  const int p = t >> 2;                            // point index
  const int q = t & 3;                             // center chunk
  const size_t pi = (size_t)b * NP + p;
  const float x0 = xyz[pi * 3 + 0], x1 = xyz[pi * 3 + 1], x2 = xyz[pi * 3 + 2];
  const float xx = x0 * x0 + x1 * x1 + x2 * x2;

  float d0 = 3.4e38f, d1 = 3.4e38f, d2 = 3.4e38f;
  int i0 = 0, i1 = 0, i2 = 0;
  const int gbase = q * 128;
  const float4* csq = cs + q * 129;
#pragma unroll 4
  for (int j = 0; j < 128; ++j) {
    float4 c = csq[j];
    float d = xx + c.w - 2.0f * (x0 * c.x + x1 * c.y + x2 * c.z);
    int g = gbase + j;
    bool c0 = d < d0, c1 = d < d1, c2 = d < d2;
    float nd2 = c1 ? d1 : (c2 ? d : d2); int ni2 = c1 ? i1 : (c2 ? g : i2);
    float nd1 = c0 ? d0 : (c1 ? d : d1); int ni1 = c0 ? i0 : (c1 ? g : i1);
    d0 = c0 ? d : d0;                    i0 = c0 ? g : i0;
    d1 = nd1; i1 = ni1; d2 = nd2; i2 = ni2;
  }
  // merge 4 lanes' top-3 (lex tie-break: smaller d, then smaller index)
#pragma unroll
  for (int off = 1; off <= 2; off <<= 1) {
    float e0 = __shfl_xor(d0, off), e1 = __shfl_xor(d1, off), e2 = __shfl_xor(d2, off);
    int j0 = __shfl_xor(i0, off), j1 = __shfl_xor(i1, off), j2 = __shfl_xor(i2, off);
#pragma unroll
    for (int s = 0; s < 3; ++s) {
      float e = (s == 0) ? e0 : (s == 1 ? e1 : e2);
      int   j = (s == 0) ? j0 : (s == 1 ? j1 : j2);
      bool c0 = (e < d0) || (e == d0 && j < i0);
      bool c1 = (e < d1) || (e == d1 && j < i1);
      bool c2 = (e < d2) || (e == d2 && j < i2);
      float nd2 = c1 ? d1 : (c2 ? e : d2); int ni2 = c1 ? i1 : (c2 ? j : i2);
      float nd1 = c0 ? d0 : (c1 ? e : d1); int ni1 = c0 ? i0 : (c1 ? j : i1);
      d0 = c0 ? e : d0;                    i0 = c0 ? j : i0;
      d1 = nd1; i1 = ni1; d2 = nd2; i2 = ni2;
    }
  }
  if (q == 0) {
    float r0 = 1.0f / (d0 + 1e-8f), r1 = 1.0f / (d1 + 1e-8f), r2 = 1.0f / (d2 + 1e-8f);
    float inv = 1.0f / (r0 + r1 + r2);
    ow[pi * 3 + 0] = r0 * inv; ow[pi * 3 + 1] = r1 * inv; ow[pi * 3 + 2] = r2 * inv;
    oidx[pi * 3 + 0] = i0; oidx[pi * 3 + 1] = i1; oidx[pi * 3 + 2] = i2;
  }
}

// ---------------- bf16 MFMA GEMM, B^T layout: out[m,n]=f(s[n]*(A.Bw+b[n])+t[n])
// A [M,K] bf16 row-major, Bw [N,K] bf16 row-major. 128x128 tile, BK=32.
// Double-buffered glds pipeline: ONE barrier per K-iter; prefetch of tile k+1
// issued after the barrier, drained by the NEXT iteration's barrier -> load
// latency hides under tile-k MFMA across all resident waves.
// XCD swizzle: xcd=id&7 owns a contiguous M range, runs all n-tiles of each
// m-tile in nearby slots -> A-tile L2 reuse (fetch /ntiles from HBM).
template <bool RELU>
__global__ __launch_bounds__(256) void gemm_bt_kernel(
    const unsigned short* __restrict__ A, const unsigned short* __restrict__ Bw,
    float* __restrict__ outp,
    const float* __restrict__ svec, const float* __restrict__ bvec,
    const float* __restrict__ tvec, int M, int N, int K, int ntiles)
{
  __shared__ unsigned short As[2 * 128 * 32];
  __shared__ unsigned short Bs[2 * 128 * 32];
  const int tid  = threadIdx.x;
  const int lane = tid & 63;
  const int wv   = tid >> 6;
  const int wm   = wv >> 1, wn = wv & 1;

  // XCD-aware block swizzle (bijective; speed heuristic only)
  const int L = blockIdx.x;
  const int xcd = L & 7, slot = L >> 3;
  const int mtper = (M >> 7) >> 3;             // m-tiles per XCD
  const int mloc = slot / ntiles;
  const int nt   = slot - mloc * ntiles;
  const int m0 = (xcd * mtper + mloc) * 128;
  const int n0 = nt * 128;

  const int crow = tid >> 2;            // 0..63
  const int ccol = (tid & 3) * 8;       // 0,8,16,24

  const unsigned short* Arow = A  + (size_t)(m0 + crow) * K + ccol;
  const unsigned short* Brow = Bw + (size_t)(n0 + crow) * K + ccol;

  // prologue: stage tile 0 into buffer 0
  glds16(Arow,                    As + wv * 512);
  glds16(Arow + (size_t)64 * K,   As + 2048 + wv * 512);
  glds16(Brow,                    Bs + wv * 512);
  glds16(Brow + (size_t)64 * K,   Bs + 2048 + wv * 512);

  const f32x4 vzero = {0.f, 0.f, 0.f, 0.f};
  f32x4 acc[4][4];
#pragma unroll
  for (int i = 0; i < 4; ++i)
#pragma unroll
    for (int j = 0; j < 4; ++j) acc[i][j] = vzero;

  for (int k0 = 0; k0 < K; k0 += 32) {
    __syncthreads();                    // drains vmcnt(0): current tile ready;
                                        // also fences prev-iter LDS reads
    const int cb = (k0 >> 5) & 1;       // buffer holding current tile
    if (k0 + 32 < K) {                  // prefetch next tile into other buffer
      unsigned short* An = As + (cb ^ 1) * 4096;
      unsigned short* Bn = Bs + (cb ^ 1) * 4096;
      glds16(Arow + k0 + 32,                  An + wv * 512);
      glds16(Arow + (size_t)64 * K + k0 + 32, An + 2048 + wv * 512);
      glds16(Brow + k0 + 32,                  Bn + wv * 512);
      glds16(Brow + (size_t)64 * K + k0 + 32, Bn + 2048 + wv * 512);
    }
    const unsigned short* Ac = As + cb * 4096;
    const unsigned short* Bc = Bs + cb * 4096;

    bf16x8 af[4], bfr[4];
#pragma unroll
    for (int mi = 0; mi < 4; ++mi) {
      ushort8v r = *(const ushort8v*)&Ac[(wm * 64 + mi * 16 + (lane & 15)) * 32 + (lane >> 4) * 8];
      af[mi] = __builtin_bit_cast(bf16x8, r);
    }
#pragma unroll
    for (int ni = 0; ni < 4; ++ni) {
      ushort8v r = *(const ushort8v*)&Bc[(wn * 64 + ni * 16 + (lane & 15)) * 32 + (lane >> 4) * 8];
      bfr[ni] = __builtin_bit_cast(bf16x8, r);
    }
#pragma unroll
    for (int mi = 0; mi < 4; ++mi)
#pragma unroll
      for (int ni = 0; ni < 4; ++ni)
        acc[mi][ni] = __builtin_amdgcn_mfma_f32_16x16x32_bf16(af[mi], bfr[ni], acc[mi][ni], 0, 0, 0);
  }

  // C/D layout: n = lane&15, m = (lane>>4)*4 + reg   [m89-verified]
#pragma unroll
  for (int mi = 0; mi < 4; ++mi) {
    int mbase = m0 + wm * 64 + mi * 16 + (lane >> 4) * 4;
#pragma unroll
    for (int ni = 0; ni < 4; ++ni) {
      int n = n0 + wn * 64 + ni * 16 + (lane & 15);
      float s = svec[n], bb = bvec[n], t = tvec[n];
      f32x4 v = acc[mi][ni];
#pragma unroll
      for (int r = 0; r < 4; ++r) {
        float val = s * (v[r] + bb) + t;
        if (RELU) val = fmaxf(val, 0.f);
        outp[(size_t)(mbase + r) * N + n] = val;
      }
    }
  }
}

// ---------------- gather + interp + ReLU -> h1 bf16 [32768,512], vectorized -
// 8 points/block; 128 lanes x float4 cover 512 channels.
__global__ __launch_bounds__(256) void interp_kernel(
    const float* __restrict__ Amat, const int* __restrict__ nidx,
    const float* __restrict__ nw, unsigned short* __restrict__ h1)
{
  const int psub = threadIdx.x >> 7;       // 0..1
  const int c4   = threadIdx.x & 127;      // float4 index
#pragma unroll
  for (int q = 0; q < 4; ++q) {
    const int pp = blockIdx.x * 8 + q * 2 + psub;
    const int b = pp >> 13;                // / 8192
    const int i0 = nidx[pp * 3 + 0], i1 = nidx[pp * 3 + 1], i2 = nidx[pp * 3 + 2];
    const float w0 = nw[pp * 3 + 0], w1v = nw[pp * 3 + 1], w2v = nw[pp * 3 + 2];
    const float4 a0 = *(const float4*)&Amat[((size_t)(b * 512 + i0)) * 512 + c4 * 4];
    const float4 a1 = *(const float4*)&Amat[((size_t)(b * 512 + i1)) * 512 + c4 * 4];
    const float4 a2 = *(const float4*)&Amat[((size_t)(b * 512 + i2)) * 512 + c4 * 4];
    ushort4 o;
    o.x = f32_to_bf16(fmaxf(w0 * a0.x + w1v * a1.x + w2v * a2.x, 0.f));
    o.y = f32_to_bf16(fmaxf(w0 * a0.y + w1v * a1.y + w2v * a2.y, 0.f));
    o.z = f32_to_bf16(fmaxf(w0 * a0.z + w1v * a1.z + w2v * a2.z, 0.f));
    o.w = f32_to_bf16(fmaxf(w0 * a0.w + w1v * a1.w + w2v * a2.w, 0.f));
    *(ushort4*)&h1[(size_t)pp * 512 + c4 * 4] = o;
  }
}

extern "C" void kernel_launch(void* const* d_in, const int* in_sizes, int n_in,
                              void* d_out, int out_size, void* d_ws, size_t ws_size,
                              hipStream_t stream) {
  const float* xyz     = (const float*)d_in[0];
  const float* centers = (const float*)d_in[1];
  const float* H4      = (const float*)d_in[2];
  const float* H8      = (const float*)d_in[3];
  const float* H12     = (const float*)d_in[4];
  const float* w1      = (const float*)d_in[5];
  const float* b1      = (const float*)d_in[6];
  const float* g1      = (const float*)d_in[7];
  const float* be1     = (const float*)d_in[8];
  const float* m1      = (const float*)d_in[9];
  const float* v1      = (const float*)d_in[10];
  const float* w2      = (const float*)d_in[11];
  const float* b2      = (const float*)d_in[12];
  const float* g2      = (const float*)d_in[13];
  const float* be2     = (const float*)d_in[14];
  const float* m2      = (const float*)d_in[15];
  const float* v2      = (const float*)d_in[16];
  float* outp = (float*)d_out;

  char* ws = (char*)d_ws;
  unsigned short* fusedb = (unsigned short*)(ws);                // 6,291,456 B
  unsigned short* w1b    = (unsigned short*)(ws + 6291456);      // 1,572,864 B
  unsigned short* w2b    = (unsigned short*)(ws + 7864320);      //   524,288 B
  float*          Amat   = (float*)         (ws + 8388608);      // 4,194,304 B
  unsigned short* h1     = (unsigned short*)(ws + 12582912);     // 33,554,432 B
  int*            nidx   = (int*)           (ws + 46137344);     //   393,216 B
  float*          nw     = (float*)         (ws + 46530560);     //   393,216 B
  float*          s1     = (float*)         (ws + 46923776);
  float* t1 = s1 + 512; float* s2 = t1 + 512; float* t2 = s2 + 512;

  scales_kernel<<<2, 256, 0, stream>>>(g1, be1, m1, v1, g2, be2, m2, v2, s1, t1, s2, t2);
  cast_fused_kernel<<<3072, 256, 0, stream>>>(H4, H8, H12, fusedb);
  cast_bf16_kernel<<<768, 256, 0, stream>>>(w1, w1b, 196608);   // 512*1536/4
  cast_bf16_kernel<<<256, 256, 0, stream>>>(w2, w2b, 65536);    // 512*512/4
  knn_kernel<<<dim3(128, 4), 256, 0, stream>>>(xyz, centers, nidx, nw);
  // fusedW + BN1 fold: Amat[m,n] = s1[n]*(fused.w1^T + b1[n]) + t1[n]
  gemm_bt_kernel<false><<<64, 256, 0, stream>>>(
      fusedb, w1b, Amat, s1, b1, t1, 2048, 512, 1536, 4);
  interp_kernel<<<4096, 256, 0, stream>>>(Amat, nidx, nw, h1);
  // out = relu(s2*(h1.w2^T + b2) + t2)
  gemm_bt_kernel<true><<<1024, 256, 0, stream>>>(
      h1, w2b, outp, s2, b2, t2, 32768, 512, 512, 4);
}